// Round 14
// baseline (462.965 us; speedup 1.0000x reference)
//
#include <hip/hip_runtime.h>

// SinkhornAttention on MI355X — MFMA f16 + XCD swizzle + exp-domain sinkhorn.
// r13 lesson: __launch_bounds__ 2nd arg did NOT raise the VGPR budget (allocator
// stuck at 64-VGPR / 8-waves-per-SIMD heuristic; state spilled to scratch ->
// L2-latency-bound at 124us). Direct control: amdgpu_waves_per_eu(2,4) ->
// allocator budget 256 VGPR -> e0..e15 truly register-resident.
// T=S=4096, B=8, E=1024, BUCKET=16 -> nb=nkb=256. TAU=0.75, ITERS=8, SCALE=1/32.
// d_out = [ out | attn_weights | log_alpha ] f32.
// Noise (verified r7): threefry2x32 partitionable, counts (0,i), draw = o0 ^ o1.

typedef float    f32x4 __attribute__((ext_vector_type(4)));
typedef _Float16 h4    __attribute__((ext_vector_type(4)));
typedef _Float16 h8    __attribute__((ext_vector_type(8)));

#define OUT_ELEMS 33554432
#define AW_ELEMS  524288

__device__ __forceinline__ void gload16(const void* g, void* l) {
  __builtin_amdgcn_global_load_lds((__attribute__((address_space(1))) void*)g,
                                   (__attribute__((address_space(3))) void*)l,
                                   16, 0, 0);
}

// ---------------- weight conversion f32 -> f16 -------------------------------
__global__ __launch_bounds__(256) void convw_k(const float* __restrict__ wq,
                                               const float* __restrict__ wk,
                                               const float* __restrict__ wo,
                                               _Float16* __restrict__ dst) {
  int which = blockIdx.y;
  const float* src = which == 0 ? wq : (which == 1 ? wk : wo);
  size_t idx = (size_t)blockIdx.x * 256 + threadIdx.x;
  f32x4 v = ((const f32x4*)src)[idx];
  ((h4*)(dst + (size_t)which * 1048576))[idx] = __builtin_convertvector(v, h4);
}

// ---------------- bucket mean over T (stride B*E), f32 -> f16 ----------------
__global__ __launch_bounds__(256) void bucket_k(const float* __restrict__ q,
                                                const float* __restrict__ k,
                                                _Float16* __restrict__ qbar,
                                                _Float16* __restrict__ kbar) {
  const float* src = blockIdx.y ? k : q;
  _Float16* dst = blockIdx.y ? kbar : qbar;
  unsigned t = blockIdx.x * 256 + threadIdx.x;                    // 0..524287
  int e4 = t & 255, i = (t >> 8) & 255, b = t >> 16;
  const f32x4* p = (const f32x4*)(src + ((size_t)(i * 16) * 8 + b) * 1024) + e4;
  f32x4 acc = {0.f, 0.f, 0.f, 0.f};
  #pragma unroll
  for (int j = 0; j < 16; ++j) acc += p[j * 2048];
  acc *= 0.0625f;
  ((h4*)(dst + (size_t)(b * 256 + i) * 1024))[e4] = __builtin_convertvector(acc, h4);
}

// ---------------- V transpose: vt[b][j][e][k] = v[(k*16+j)][b][e], f32->f16 --
__global__ __launch_bounds__(256) void vtrans_k(const float* __restrict__ v,
                                                _Float16* __restrict__ vt) {
  int bid = blockIdx.x;
  int kb = bid & 3, eb = (bid >> 2) & 15, j = (bid >> 6) & 15, b = bid >> 10;
  int k0 = kb * 64, e0 = eb * 64;
  __shared__ _Float16 tile[64][72];
  int t = threadIdx.x, r = t >> 2, qq = t & 3;
  const float* src = v + ((size_t)((k0 + r) * 16 + j) * 8 + b) * 1024 + e0;
  #pragma unroll
  for (int ii = 0; ii < 4; ++ii) {
    f32x4 x = ((const f32x4*)src)[qq + ii * 4];
    *(h4*)&tile[r][(qq + ii * 4) * 4] = __builtin_convertvector(x, h4);
  }
  __syncthreads();
  _Float16* dstp = vt + (((size_t)(b * 16 + j) * 1024 + e0 + r) * 256 + k0 + qq * 16);
  h8 o0, o1;
  #pragma unroll
  for (int kk = 0; kk < 8; ++kk) o0[kk] = tile[qq * 16 + kk][r];
  #pragma unroll
  for (int kk = 0; kk < 8; ++kk) o1[kk] = tile[qq * 16 + 8 + kk][r];
  *(h8*)dstp = o0;
  *(h8*)(dstp + 8) = o1;
}

// ---------------- JAX threefry2x32 gumbel (verified r7) ----------------------
// Writes EXP-DOMAIN entries: e = exp((logits + g)/tau). Max la ~ 21.5 -> 2.2e9,
// safely fp32-finite; sinkhorn runs multiplicatively (identical arithmetic).
__device__ __forceinline__ unsigned rotl32(unsigned x, int r) {
  return (x << r) | (x >> (32 - r));
}
__global__ __launch_bounds__(256) void gumbel_k(const float* __restrict__ logits,
                                                float* __restrict__ ebuf) {
  unsigned i = blockIdx.x * 256 + threadIdx.x;                    // 0..524287
  const unsigned k0 = 0u, k1 = 42u, k2 = 0u ^ 42u ^ 0x1BD11BDAu;
  unsigned x0 = 0u + k0, x1 = i + k1;                             // counts (hi,lo)=(0,i)
#define R4(a,b,c,d) \
  x0 += x1; x1 = rotl32(x1, a); x1 ^= x0; \
  x0 += x1; x1 = rotl32(x1, b); x1 ^= x0; \
  x0 += x1; x1 = rotl32(x1, c); x1 ^= x0; \
  x0 += x1; x1 = rotl32(x1, d); x1 ^= x0;
  R4(13,15,26,6)  x0 += k1; x1 += k2 + 1u;
  R4(17,29,16,24) x0 += k2; x1 += k0 + 2u;
  R4(13,15,26,6)  x0 += k0; x1 += k1 + 3u;
  R4(17,29,16,24) x0 += k1; x1 += k2 + 4u;
  R4(13,15,26,6)  x0 += k2; x1 += k0 + 5u;
#undef R4
  unsigned bits = x0 ^ x1;
  float u = __builtin_bit_cast(float, (bits >> 9) | 0x3f800000u) - 1.0f;
  float g = -logf(-logf(u + 1e-6f) + 1e-6f);
  ebuf[i] = __expf((logits[i] + g) / 0.75f);
}

// ---------------- fused Sinkhorn (exp domain, named registers) ---------------
// Thread t: row r=t>>2, quarter p=t&3 -> entries e0..e15 (f32x4 each) hold
// E[b][r][p*64..p*64+63] * (deferred col scale). cl[] holds INVERSE col sums.
#define E16(OP) OP(0) OP(1) OP(2) OP(3) OP(4) OP(5) OP(6) OP(7) \
                OP(8) OP(9) OP(10) OP(11) OP(12) OP(13) OP(14) OP(15)
__global__
__attribute__((amdgpu_flat_work_group_size(1024, 1024), amdgpu_waves_per_eu(2, 4)))
void sink_fused_k(const float* __restrict__ ein,
                  float* __restrict__ attnw,
                  _Float16* __restrict__ wsh) {
  const int b = blockIdx.x;
  const int t = threadIdx.x;
  const int p = t & 3;
  const int wv = t >> 6, lane = t & 63;
  const size_t rowoff = (size_t)b * 65536 + (size_t)(t >> 2) * 256 + p * 64;
  const f32x4* gin = (const f32x4*)(ein + rowoff);

#define DECL(i) f32x4 e##i = gin[i];
  E16(DECL)
#undef DECL

  __shared__ float cl[4 * 68];         // inverse col sums; stride 68 -> 16B-aligned
  __shared__ float wpart[16][256];     // per-wave col partials [wv][elem*4+p]
  if (t < 256) cl[(t >> 6) * 68 + (t & 63)] = 1.0f;
  __syncthreads();

  const float* clq = &cl[p * 68];

  for (int it = 0; it < 8; ++it) {
    // ---- row pass: e *= inv_cs[col]; e *= 1/rowsum ----
#define APPC(i) { f32x4 c = *(const f32x4*)&clq[i * 4]; e##i *= c; }
    E16(APPC)
#undef APPC
    f32x4 s4 = (((e0 + e1) + (e2 + e3)) + ((e4 + e5) + (e6 + e7)))
             + (((e8 + e9) + (e10 + e11)) + ((e12 + e13) + (e14 + e15)));
    float rs = (s4[0] + s4[1]) + (s4[2] + s4[3]);
    rs += __shfl_xor(rs, 1, 64);
    rs += __shfl_xor(rs, 2, 64);
    float irs = 1.0f / rs;
#define APPR(i) e##i *= irs;
    E16(APPR)
#undef APPR
    // ---- per-wave column partial sums (16 rows per wave) ----
#define CSUM(i) { \
    float v0 = e##i[0], v1 = e##i[1], v2 = e##i[2], v3 = e##i[3]; \
    v0 += __shfl_xor(v0, 4, 64); v0 += __shfl_xor(v0, 8, 64); \
    v0 += __shfl_xor(v0, 16, 64); v0 += __shfl_xor(v0, 32, 64); \
    v1 += __shfl_xor(v1, 4, 64); v1 += __shfl_xor(v1, 8, 64); \
    v1 += __shfl_xor(v1, 16, 64); v1 += __shfl_xor(v1, 32, 64); \
    v2 += __shfl_xor(v2, 4, 64); v2 += __shfl_xor(v2, 8, 64); \
    v2 += __shfl_xor(v2, 16, 64); v2 += __shfl_xor(v2, 32, 64); \
    v3 += __shfl_xor(v3, 4, 64); v3 += __shfl_xor(v3, 8, 64); \
    v3 += __shfl_xor(v3, 16, 64); v3 += __shfl_xor(v3, 32, 64); \
    if (lane < 4) { \
      float* wp = &wpart[wv][i * 16]; \
      wp[lane] = v0; wp[4 + lane] = v1; wp[8 + lane] = v2; wp[12 + lane] = v3; \
    } }
    E16(CSUM)
#undef CSUM
    __syncthreads();
    if (t < 256) {
      int pp = t >> 6, ii = t & 63;
      float ss = 0.f;
      #pragma unroll
      for (int w = 0; w < 16; ++w) ss += wpart[w][ii * 4 + pp];
      cl[pp * 68 + ii] = 1.0f / ss;
    }
    __syncthreads();
  }

  // ---- final: w = e * inv_cs ----
  f32x4* aw = (f32x4*)(attnw + rowoff);
  h4* wh = (h4*)(wsh + rowoff);
#define FIN(i) { \
  f32x4 c = *(const f32x4*)&clq[i * 4]; \
  f32x4 w = e##i * c; \
  aw[i] = w; \
  h4 hv; hv[0] = (_Float16)w[0]; hv[1] = (_Float16)w[1]; \
  hv[2] = (_Float16)w[2]; hv[3] = (_Float16)w[3]; \
  wh[i] = hv; }
  E16(FIN)
#undef FIN
}

// ---------------- generic 128x128 NT MFMA GEMM (m97 structure) ---------------
// C[M,N] = A[M,K] @ B[N,K]^T ; A,B f16 K-contiguous. 256 thr, 4 waves, BK=32.
// MODE 0: proj    (1-D grid 128, XCD-chunked)  -> f16 out + bias
// MODE 1: logits  (3-D grid)                   -> f32 /32 to log_alpha
// MODE 2: attn    (1-D grid 2048, XCD-chunked) -> f16 attnh
// MODE 3: outproj (1-D grid 2048, XCD-chunked) -> f32 out + bias
template <int MODE>
__global__ __launch_bounds__(256) void gemm128(const _Float16* __restrict__ A,
                                               const _Float16* __restrict__ B,
                                               const float* __restrict__ bias,
                                               void* __restrict__ out0,
                                               int K, int lda, int ldb) {
  const int tid = threadIdx.x, lane = tid & 63, w = tid >> 6;
  int bx = blockIdx.x, by = blockIdx.y, bz = blockIdx.z;
  if constexpr (MODE == 0) {           // grid 128: wid -> m=wid>>3 (16), n=wid&7
    int wid = ((bx & 7) << 4) + (bx >> 3);
    by = wid & 7; bx = wid >> 3;
  }
  if constexpr (MODE == 2) {           // grid 2048: x(2) fastest, y(8), z(128)
    int wid = ((bx & 7) << 8) + (bx >> 3);
    bz = wid >> 4; by = (wid >> 1) & 7; bx = wid & 1;
  }
  if constexpr (MODE == 3) {           // grid 2048: m=wid>>3 (256), n=wid&7
    int wid = ((bx & 7) << 8) + (bx >> 3);
    by = wid & 7; bx = wid >> 3;
  }
  const int m0 = bx * 128, n0 = by * 128;
  const _Float16* Ab = A;
  const _Float16* Bb = B;
  if constexpr (MODE == 1) { Ab += (size_t)bz * 262144; Bb += (size_t)bz * 262144; }
  if constexpr (MODE == 2) { Ab += (size_t)(bz >> 4) * 65536; Bb += (size_t)bz * 262144; }
  __shared__ _Float16 lA[128 * 32];
  __shared__ _Float16 lB[128 * 32];
  f32x4 acc[4][4] = {};
  const int wm = (w >> 1) * 64, wn = (w & 1) * 64;
  const int fr = lane & 15, fk = (lane >> 4) * 8;
  const int q0 = tid, q1 = tid + 256;

  for (int kt = 0; kt < K; kt += 32) {
    __syncthreads();
    gload16(Ab + (size_t)(m0 + (q0 >> 2)) * lda + kt + (q0 & 3) * 8, &lA[(w * 64) * 8]);
    gload16(Ab + (size_t)(m0 + (q1 >> 2)) * lda + kt + (q1 & 3) * 8, &lA[(256 + w * 64) * 8]);
    gload16(Bb + (size_t)(n0 + (q0 >> 2)) * ldb + kt + (q0 & 3) * 8, &lB[(w * 64) * 8]);
    gload16(Bb + (size_t)(n0 + (q1 >> 2)) * ldb + kt + (q1 & 3) * 8, &lB[(256 + w * 64) * 8]);
    __syncthreads();
    h8 af[4], bf[4];
    #pragma unroll
    for (int i = 0; i < 4; ++i) {
      af[i] = *(const h8*)&lA[(wm + i * 16 + fr) * 32 + fk];
      bf[i] = *(const h8*)&lB[(wn + i * 16 + fr) * 32 + fk];
    }
    #pragma unroll
    for (int mi = 0; mi < 4; ++mi)
      #pragma unroll
      for (int ni = 0; ni < 4; ++ni)
        acc[mi][ni] = __builtin_amdgcn_mfma_f32_16x16x32_f16(af[mi], bf[ni], acc[mi][ni], 0, 0, 0);
  }

  const int er = (lane >> 4) * 4;
  #pragma unroll
  for (int mi = 0; mi < 4; ++mi) {
    #pragma unroll
    for (int ni = 0; ni < 4; ++ni) {
      #pragma unroll
      for (int r = 0; r < 4; ++r) {
        int row = m0 + wm + mi * 16 + er + r;
        int col = n0 + wn + ni * 16 + fr;
        float val = acc[mi][ni][r];
        if constexpr (MODE == 0) {
          ((_Float16*)out0)[(size_t)row * 1024 + col] = (_Float16)(val + bias[col]);
        } else if constexpr (MODE == 1) {
          ((float*)out0)[(size_t)bz * 65536 + row * 256 + col] = val * 0.03125f;
        } else if constexpr (MODE == 2) {
          int b = bz >> 4, j = bz & 15;
          ((_Float16*)out0)[((size_t)(b * 4096 + row * 16 + j)) * 1024 + col] = (_Float16)val;
        } else {
          int bb = row >> 12, t = row & 4095;
          ((float*)out0)[((size_t)t * 8 + bb) * 1024 + col] = val + bias[col];
        }
      }
    }
  }
}

// -----------------------------------------------------------------------------
extern "C" void kernel_launch(void* const* d_in, const int* in_sizes, int n_in,
                              void* d_out, int out_size, void* d_ws, size_t ws_size,
                              hipStream_t stream) {
  const float* query = (const float*)d_in[0];
  const float* key   = (const float*)d_in[1];
  const float* value = (const float*)d_in[2];
  const float* wq    = (const float*)d_in[3];
  const float* bq    = (const float*)d_in[4];
  const float* wk    = (const float*)d_in[5];
  const float* bk    = (const float*)d_in[6];
  const float* wo    = (const float*)d_in[7];
  const float* bo    = (const float*)d_in[8];

  float* out      = (float*)d_out;
  float* attnw    = out + OUT_ELEMS;            // 8*256*256
  float* logalpha = out + OUT_ELEMS + AW_ELEMS; // logits (pre-noise)

  char* ws = (char*)d_ws;
  const size_t MB = 1024 * 1024;
  _Float16* wqh   = (_Float16*)(ws + 0 * MB);   // 2 MB
  _Float16* wkh   = (_Float16*)(ws + 2 * MB);   // 2 MB
  _Float16* woh   = (_Float16*)(ws + 4 * MB);   // 2 MB
  _Float16* qbar  = (_Float16*)(ws + 6 * MB);   // 4 MB  (2048x1024)
  _Float16* kbar  = (_Float16*)(ws + 10 * MB);  // 4 MB
  _Float16* qbh   = (_Float16*)(ws + 14 * MB);  // 4 MB
  _Float16* kbh   = (_Float16*)(ws + 18 * MB);  // 4 MB
  float*    ebuf  = (float*)(ws + 22 * MB);     // 2 MB  exp-domain entries
  _Float16* wsh   = (_Float16*)(ws + 25 * MB);  // 1 MB  attn weights f16
  _Float16* vt    = (_Float16*)(ws + 26 * MB);  // 64 MB vt[b][j][e][k]
  _Float16* attnh = (_Float16*)(ws + 90 * MB);  // 64 MB attn (B,T,E) f16
  (void)in_sizes; (void)n_in; (void)out_size; (void)ws_size;

  convw_k<<<dim3(1024, 3), 256, 0, stream>>>(wq, wk, wo, wqh);
  bucket_k<<<dim3(2048, 2), 256, 0, stream>>>(query, key, qbar, kbar);
  vtrans_k<<<dim3(8192), 256, 0, stream>>>(value, vt);

  gemm128<0><<<dim3(128), 256, 0, stream>>>(qbar, wqh, bq, qbh, 1024, 1024, 1024);
  gemm128<0><<<dim3(128), 256, 0, stream>>>(kbar, wkh, bk, kbh, 1024, 1024, 1024);
  gemm128<1><<<dim3(2, 2, 8), 256, 0, stream>>>(qbh, kbh, nullptr, logalpha, 1024, 1024, 1024);

  gumbel_k<<<dim3(2048), 256, 0, stream>>>(logalpha, ebuf);
  sink_fused_k<<<dim3(8), 1024, 0, stream>>>(ebuf, attnw, wsh);

  gemm128<2><<<dim3(2048), 256, 0, stream>>>(wsh, vt, nullptr, attnh, 256, 256, 256);
  gemm128<3><<<dim3(2048), 256, 0, stream>>>(attnh, woh, bo, out, 1024, 1024, 1024);
}

// Round 15
// 400.143 us; speedup vs baseline: 1.1570x; 1.1570x over previous
//
#include <hip/hip_runtime.h>

// SinkhornAttention on MI355X — MFMA f16 + XCD swizzle + scaling-vector sinkhorn.
// r14 lesson: per-thread 64-float state spills regardless of launch_bounds /
// waves_per_eu (VGPR stuck at 64). Fix: iterate sinkhorn's DIAGONAL SCALINGS
// only — state is always diag(a)·E·diag(b), so iterate a,b (LDS) against
// read-only exp-domain E (global, L2-resident). W = diag(a8)·E·diag(b8).
// T=S=4096, B=8, E=1024, BUCKET=16 -> nb=nkb=256. TAU=0.75, ITERS=8, SCALE=1/32.
// d_out = [ out | attn_weights | log_alpha ] f32.
// Noise (verified r7): threefry2x32 partitionable, counts (0,i), draw = o0 ^ o1.

typedef float    f32x4 __attribute__((ext_vector_type(4)));
typedef _Float16 h4    __attribute__((ext_vector_type(4)));
typedef _Float16 h8    __attribute__((ext_vector_type(8)));

#define OUT_ELEMS 33554432
#define AW_ELEMS  524288

__device__ __forceinline__ void gload16(const void* g, void* l) {
  __builtin_amdgcn_global_load_lds((__attribute__((address_space(1))) void*)g,
                                   (__attribute__((address_space(3))) void*)l,
                                   16, 0, 0);
}

// ---------------- weight conversion f32 -> f16 -------------------------------
__global__ __launch_bounds__(256) void convw_k(const float* __restrict__ wq,
                                               const float* __restrict__ wk,
                                               const float* __restrict__ wo,
                                               _Float16* __restrict__ dst) {
  int which = blockIdx.y;
  const float* src = which == 0 ? wq : (which == 1 ? wk : wo);
  size_t idx = (size_t)blockIdx.x * 256 + threadIdx.x;
  f32x4 v = ((const f32x4*)src)[idx];
  ((h4*)(dst + (size_t)which * 1048576))[idx] = __builtin_convertvector(v, h4);
}

// ---------------- bucket mean over T (stride B*E), f32 -> f16 ----------------
__global__ __launch_bounds__(256) void bucket_k(const float* __restrict__ q,
                                                const float* __restrict__ k,
                                                _Float16* __restrict__ qbar,
                                                _Float16* __restrict__ kbar) {
  const float* src = blockIdx.y ? k : q;
  _Float16* dst = blockIdx.y ? kbar : qbar;
  unsigned t = blockIdx.x * 256 + threadIdx.x;                    // 0..524287
  int e4 = t & 255, i = (t >> 8) & 255, b = t >> 16;
  const f32x4* p = (const f32x4*)(src + ((size_t)(i * 16) * 8 + b) * 1024) + e4;
  f32x4 acc = {0.f, 0.f, 0.f, 0.f};
  #pragma unroll
  for (int j = 0; j < 16; ++j) acc += p[j * 2048];
  acc *= 0.0625f;
  ((h4*)(dst + (size_t)(b * 256 + i) * 1024))[e4] = __builtin_convertvector(acc, h4);
}

// ---------------- V transpose: vt[b][j][e][k] = v[(k*16+j)][b][e], f32->f16 --
__global__ __launch_bounds__(256) void vtrans_k(const float* __restrict__ v,
                                                _Float16* __restrict__ vt) {
  int bid = blockIdx.x;
  int kb = bid & 3, eb = (bid >> 2) & 15, j = (bid >> 6) & 15, b = bid >> 10;
  int k0 = kb * 64, e0 = eb * 64;
  __shared__ _Float16 tile[64][72];
  int t = threadIdx.x, r = t >> 2, qq = t & 3;
  const float* src = v + ((size_t)((k0 + r) * 16 + j) * 8 + b) * 1024 + e0;
  #pragma unroll
  for (int ii = 0; ii < 4; ++ii) {
    f32x4 x = ((const f32x4*)src)[qq + ii * 4];
    *(h4*)&tile[r][(qq + ii * 4) * 4] = __builtin_convertvector(x, h4);
  }
  __syncthreads();
  _Float16* dstp = vt + (((size_t)(b * 16 + j) * 1024 + e0 + r) * 256 + k0 + qq * 16);
  h8 o0, o1;
  #pragma unroll
  for (int kk = 0; kk < 8; ++kk) o0[kk] = tile[qq * 16 + kk][r];
  #pragma unroll
  for (int kk = 0; kk < 8; ++kk) o1[kk] = tile[qq * 16 + 8 + kk][r];
  *(h8*)dstp = o0;
  *(h8*)(dstp + 8) = o1;
}

// ---------------- JAX threefry2x32 gumbel (verified r7) ----------------------
// Writes EXP-DOMAIN entries: e = exp((logits + g)/tau). Max la ~ 21.5 -> 2.2e9,
// safely fp32-finite (validated r12-r14: absmax identical to log-domain).
__device__ __forceinline__ unsigned rotl32(unsigned x, int r) {
  return (x << r) | (x >> (32 - r));
}
__global__ __launch_bounds__(256) void gumbel_k(const float* __restrict__ logits,
                                                float* __restrict__ ebuf) {
  unsigned i = blockIdx.x * 256 + threadIdx.x;                    // 0..524287
  const unsigned k0 = 0u, k1 = 42u, k2 = 0u ^ 42u ^ 0x1BD11BDAu;
  unsigned x0 = 0u + k0, x1 = i + k1;                             // counts (hi,lo)=(0,i)
#define R4(a,b,c,d) \
  x0 += x1; x1 = rotl32(x1, a); x1 ^= x0; \
  x0 += x1; x1 = rotl32(x1, b); x1 ^= x0; \
  x0 += x1; x1 = rotl32(x1, c); x1 ^= x0; \
  x0 += x1; x1 = rotl32(x1, d); x1 ^= x0;
  R4(13,15,26,6)  x0 += k1; x1 += k2 + 1u;
  R4(17,29,16,24) x0 += k2; x1 += k0 + 2u;
  R4(13,15,26,6)  x0 += k0; x1 += k1 + 3u;
  R4(17,29,16,24) x0 += k1; x1 += k2 + 4u;
  R4(13,15,26,6)  x0 += k2; x1 += k0 + 5u;
#undef R4
  unsigned bits = x0 ^ x1;
  float u = __builtin_bit_cast(float, (bits >> 9) | 0x3f800000u) - 1.0f;
  float g = -logf(-logf(u + 1e-6f) + 1e-6f);
  ebuf[i] = __expf((logits[i] + g) / 0.75f);
}

// ---------------- Sinkhorn via scaling vectors: 1 block/batch ----------------
// a <- 1/(E b) ; b <- 1/(E^T a), 8 iterations, init b=1. W = a_q * E * b_k.
// Row sweep: thread (r=t>>2, p=t&3) dots 16 f32x4 of E-row against LDS b.
// Col sweep: thread (k=t&255, g=t>>8) sums 64 rows (coalesced) against LDS a.
__global__ __launch_bounds__(1024) void sink_rc_k(const float* __restrict__ ein,
                                                  float* __restrict__ attnw,
                                                  _Float16* __restrict__ wsh) {
  const int b = blockIdx.x;
  const int t = threadIdx.x;
  const int r = t >> 2, p = t & 3;       // row-sweep role
  const int k = t & 255, g = t >> 8;     // col-sweep role
  const float* Eb = ein + (size_t)b * 65536;
  const f32x4* Eb4 = (const f32x4*)Eb;

  __shared__ float ra[256];
  __shared__ float cb[256];
  __shared__ float part[4][256];
  if (t < 256) cb[t] = 1.0f;
  __syncthreads();

  const f32x4* cb4 = (const f32x4*)cb;

  for (int it = 0; it < 8; ++it) {
    // ---- a = 1/(E·b) ----
    float s = 0.f;
    #pragma unroll
    for (int i = 0; i < 16; ++i) {
      f32x4 e = Eb4[r * 64 + p * 16 + i];
      f32x4 c = cb4[p * 16 + i];
      f32x4 m = e * c;
      s += (m[0] + m[1]) + (m[2] + m[3]);
    }
    s += __shfl_xor(s, 1, 64);
    s += __shfl_xor(s, 2, 64);
    if (p == 0) ra[r] = 1.0f / s;
    __syncthreads();
    // ---- b = 1/(E^T·a) ----
    float s2 = 0.f;
    #pragma unroll 8
    for (int q2 = 0; q2 < 64; ++q2) {
      int row = g * 64 + q2;
      s2 += Eb[row * 256 + k] * ra[row];
    }
    part[g][k] = s2;
    __syncthreads();
    if (t < 256) {
      cb[t] = 1.0f / (part[0][t] + part[1][t] + part[2][t] + part[3][t]);
    }
    __syncthreads();
  }

  // ---- final: W = ra[r] * E * cb[k] ----
  const float arow = ra[r];
  f32x4* aw = (f32x4*)(attnw + (size_t)b * 65536 + r * 256 + p * 64);
  h4* wh = (h4*)(wsh + (size_t)b * 65536 + r * 256 + p * 64);
  #pragma unroll
  for (int i = 0; i < 16; ++i) {
    f32x4 e = Eb4[r * 64 + p * 16 + i];
    f32x4 c = cb4[p * 16 + i];
    f32x4 w = e * c * arow;
    aw[i] = w;
    h4 hv;
    hv[0] = (_Float16)w[0]; hv[1] = (_Float16)w[1];
    hv[2] = (_Float16)w[2]; hv[3] = (_Float16)w[3];
    wh[i] = hv;
  }
}

// ---------------- generic 128x128 NT MFMA GEMM (m97 structure) ---------------
// C[M,N] = A[M,K] @ B[N,K]^T ; A,B f16 K-contiguous. 256 thr, 4 waves, BK=32.
// MODE 0: proj    (1-D grid 128, XCD-chunked)  -> f16 out + bias
// MODE 1: logits  (3-D grid)                   -> f32 /32 to log_alpha
// MODE 2: attn    (1-D grid 2048, XCD-chunked) -> f16 attnh
// MODE 3: outproj (1-D grid 2048, XCD-chunked) -> f32 out + bias
template <int MODE>
__global__ __launch_bounds__(256) void gemm128(const _Float16* __restrict__ A,
                                               const _Float16* __restrict__ B,
                                               const float* __restrict__ bias,
                                               void* __restrict__ out0,
                                               int K, int lda, int ldb) {
  const int tid = threadIdx.x, lane = tid & 63, w = tid >> 6;
  int bx = blockIdx.x, by = blockIdx.y, bz = blockIdx.z;
  if constexpr (MODE == 0) {           // grid 128: wid -> m=wid>>3 (16), n=wid&7
    int wid = ((bx & 7) << 4) + (bx >> 3);
    by = wid & 7; bx = wid >> 3;
  }
  if constexpr (MODE == 2) {           // grid 2048: x(2) fastest, y(8), z(128)
    int wid = ((bx & 7) << 8) + (bx >> 3);
    bz = wid >> 4; by = (wid >> 1) & 7; bx = wid & 1;
  }
  if constexpr (MODE == 3) {           // grid 2048: m=wid>>3 (256), n=wid&7
    int wid = ((bx & 7) << 8) + (bx >> 3);
    by = wid & 7; bx = wid >> 3;
  }
  const int m0 = bx * 128, n0 = by * 128;
  const _Float16* Ab = A;
  const _Float16* Bb = B;
  if constexpr (MODE == 1) { Ab += (size_t)bz * 262144; Bb += (size_t)bz * 262144; }
  if constexpr (MODE == 2) { Ab += (size_t)(bz >> 4) * 65536; Bb += (size_t)bz * 262144; }
  __shared__ _Float16 lA[128 * 32];
  __shared__ _Float16 lB[128 * 32];
  f32x4 acc[4][4] = {};
  const int wm = (w >> 1) * 64, wn = (w & 1) * 64;
  const int fr = lane & 15, fk = (lane >> 4) * 8;
  const int q0 = tid, q1 = tid + 256;

  for (int kt = 0; kt < K; kt += 32) {
    __syncthreads();
    gload16(Ab + (size_t)(m0 + (q0 >> 2)) * lda + kt + (q0 & 3) * 8, &lA[(w * 64) * 8]);
    gload16(Ab + (size_t)(m0 + (q1 >> 2)) * lda + kt + (q1 & 3) * 8, &lA[(256 + w * 64) * 8]);
    gload16(Bb + (size_t)(n0 + (q0 >> 2)) * ldb + kt + (q0 & 3) * 8, &lB[(w * 64) * 8]);
    gload16(Bb + (size_t)(n0 + (q1 >> 2)) * ldb + kt + (q1 & 3) * 8, &lB[(256 + w * 64) * 8]);
    __syncthreads();
    h8 af[4], bf[4];
    #pragma unroll
    for (int i = 0; i < 4; ++i) {
      af[i] = *(const h8*)&lA[(wm + i * 16 + fr) * 32 + fk];
      bf[i] = *(const h8*)&lB[(wn + i * 16 + fr) * 32 + fk];
    }
    #pragma unroll
    for (int mi = 0; mi < 4; ++mi)
      #pragma unroll
      for (int ni = 0; ni < 4; ++ni)
        acc[mi][ni] = __builtin_amdgcn_mfma_f32_16x16x32_f16(af[mi], bf[ni], acc[mi][ni], 0, 0, 0);
  }

  const int er = (lane >> 4) * 4;
  #pragma unroll
  for (int mi = 0; mi < 4; ++mi) {
    #pragma unroll
    for (int ni = 0; ni < 4; ++ni) {
      #pragma unroll
      for (int r = 0; r < 4; ++r) {
        int row = m0 + wm + mi * 16 + er + r;
        int col = n0 + wn + ni * 16 + fr;
        float val = acc[mi][ni][r];
        if constexpr (MODE == 0) {
          ((_Float16*)out0)[(size_t)row * 1024 + col] = (_Float16)(val + bias[col]);
        } else if constexpr (MODE == 1) {
          ((float*)out0)[(size_t)bz * 65536 + row * 256 + col] = val * 0.03125f;
        } else if constexpr (MODE == 2) {
          int b = bz >> 4, j = bz & 15;
          ((_Float16*)out0)[((size_t)(b * 4096 + row * 16 + j)) * 1024 + col] = (_Float16)val;
        } else {
          int bb = row >> 12, t = row & 4095;
          ((float*)out0)[((size_t)t * 8 + bb) * 1024 + col] = val + bias[col];
        }
      }
    }
  }
}

// -----------------------------------------------------------------------------
extern "C" void kernel_launch(void* const* d_in, const int* in_sizes, int n_in,
                              void* d_out, int out_size, void* d_ws, size_t ws_size,
                              hipStream_t stream) {
  const float* query = (const float*)d_in[0];
  const float* key   = (const float*)d_in[1];
  const float* value = (const float*)d_in[2];
  const float* wq    = (const float*)d_in[3];
  const float* bq    = (const float*)d_in[4];
  const float* wk    = (const float*)d_in[5];
  const float* bk    = (const float*)d_in[6];
  const float* wo    = (const float*)d_in[7];
  const float* bo    = (const float*)d_in[8];

  float* out      = (float*)d_out;
  float* attnw    = out + OUT_ELEMS;            // 8*256*256
  float* logalpha = out + OUT_ELEMS + AW_ELEMS; // logits (pre-noise)

  char* ws = (char*)d_ws;
  const size_t MB = 1024 * 1024;
  _Float16* wqh   = (_Float16*)(ws + 0 * MB);   // 2 MB
  _Float16* wkh   = (_Float16*)(ws + 2 * MB);   // 2 MB
  _Float16* woh   = (_Float16*)(ws + 4 * MB);   // 2 MB
  _Float16* qbar  = (_Float16*)(ws + 6 * MB);   // 4 MB  (2048x1024)
  _Float16* kbar  = (_Float16*)(ws + 10 * MB);  // 4 MB
  _Float16* qbh   = (_Float16*)(ws + 14 * MB);  // 4 MB
  _Float16* kbh   = (_Float16*)(ws + 18 * MB);  // 4 MB
  float*    ebuf  = (float*)(ws + 22 * MB);     // 2 MB  exp-domain entries
  _Float16* wsh   = (_Float16*)(ws + 25 * MB);  // 1 MB  attn weights f16
  _Float16* vt    = (_Float16*)(ws + 26 * MB);  // 64 MB vt[b][j][e][k]
  _Float16* attnh = (_Float16*)(ws + 90 * MB);  // 64 MB attn (B,T,E) f16
  (void)in_sizes; (void)n_in; (void)out_size; (void)ws_size;

  convw_k<<<dim3(1024, 3), 256, 0, stream>>>(wq, wk, wo, wqh);
  bucket_k<<<dim3(2048, 2), 256, 0, stream>>>(query, key, qbar, kbar);
  vtrans_k<<<dim3(8192), 256, 0, stream>>>(value, vt);

  gemm128<0><<<dim3(128), 256, 0, stream>>>(qbar, wqh, bq, qbh, 1024, 1024, 1024);
  gemm128<0><<<dim3(128), 256, 0, stream>>>(kbar, wkh, bk, kbh, 1024, 1024, 1024);
  gemm128<1><<<dim3(2, 2, 8), 256, 0, stream>>>(qbh, kbh, nullptr, logalpha, 1024, 1024, 1024);

  gumbel_k<<<dim3(2048), 256, 0, stream>>>(logalpha, ebuf);
  sink_rc_k<<<dim3(8), 1024, 0, stream>>>(ebuf, attnw, wsh);

  gemm128<2><<<dim3(2048), 256, 0, stream>>>(wsh, vt, nullptr, attnh, 256, 256, 256);
  gemm128<3><<<dim3(2048), 256, 0, stream>>>(attnh, woh, bo, out, 1024, 1024, 1024);
}